// Round 18
// baseline (47.229 us; speedup 1.0000x reference)
//
#include <hip/hip_runtime.h>
#include <hip/hip_bf16.h>

#define BATCH 8
#define SEQ   2048
#define DIM   512
#define HD    64
#define NEGV  (-1e30f)
#define ROWS  (BATCH * SEQ)   // 16384

typedef float f32x4  __attribute__((ext_vector_type(4)));
typedef int   i32x4  __attribute__((ext_vector_type(4)));
typedef short bf16x8 __attribute__((ext_vector_type(8)));
typedef short bf16x4 __attribute__((ext_vector_type(4)));
typedef unsigned short u16x4 __attribute__((ext_vector_type(4)));

__device__ __forceinline__ short f2bf(float f) {
  unsigned u = __builtin_bit_cast(unsigned, f);
  u += 0x7fffu + ((u >> 16) & 1u);
  return (short)(u >> 16);
}
__device__ __forceinline__ float bf2f(unsigned short s) {
  return __builtin_bit_cast(float, (unsigned)s << 16);
}

// async global->LDS, 16B per lane; dest = wave-uniform base + lane*16
__device__ __forceinline__ void gload16(const void* gsrc, void* ldst) {
  __builtin_amdgcn_global_load_lds(
      (const __attribute__((address_space(1))) unsigned int*)gsrc,
      (__attribute__((address_space(3))) unsigned int*)ldst,
      16, 0, 0);
}

// ---------------- Kernel 0: W transpose+convert + additive mask -------------
__global__ __launch_bounds__(256) void prep_w(
    const float* __restrict__ Wq, const float* __restrict__ Wk,
    const float* __restrict__ Wv, const unsigned char* __restrict__ pmask,
    short* __restrict__ Wt, float* __restrict__ maskF)
{
  __shared__ float lds[64][65];
  const int mat = blockIdx.x % 3;
  const int kb  = blockIdx.x / 3;
  const float* W = mat == 0 ? Wq : (mat == 1 ? Wk : Wv);
  const int tid = threadIdx.x;

  #pragma unroll
  for (int i = 0; i < 4; ++i) {
    const int kr = i * 16 + (tid >> 4);
    const int col = (tid & 15) * 4;
    *(float4*)&lds[kr][col] = *(const float4*)&W[(kb * 64 + kr) * HD + col];
  }
  __syncthreads();
  #pragma unroll
  for (int i = 0; i < 2; ++i) {
    const int c = tid + i * 256;
    const int n = c >> 3, seg = c & 7;
    bf16x8 o;
    #pragma unroll
    for (int j = 0; j < 8; ++j) o[j] = f2bf(lds[seg * 8 + j][n]);
    *(bf16x8*)&Wt[(mat * 64 + n) * DIM + kb * 64 + seg * 8] = o;
  }

  // additive mask in exp2 domain: pmask ? -1e30*log2(e) : 0
  for (int i = blockIdx.x * 256 + tid; i < ROWS; i += 24 * 256)
    maskF[i] = pmask[i] ? -1.442695041e30f : 0.f;
}

// ---------------- Kernel 1: QKV via MFMA, 256 thr, 32-row tile, BK=64 -------
// Grid 512 = 2 blocks/CU (R17, verified best).
__global__ __launch_bounds__(256) void qkv_gemm(
    const float* __restrict__ x, const short* __restrict__ Wt,
    const float* __restrict__ bq, const float* __restrict__ bk,
    const float* __restrict__ bv,
    short* __restrict__ Qb, short* __restrict__ Kb, short* __restrict__ Vt)
{
  __shared__ short xs[32 * 72];    // [row][k], padded stride 72
  __shared__ short ws[192 * 72];   // [col][k]

  const int tid  = threadIdx.x;
  const int lane = tid & 63;
  const int w    = tid >> 6;       // 0..3: cols w*48..+47
  const int lc   = lane & 15;
  const int lg   = lane >> 4;
  const long r0  = (long)blockIdx.x * 32;

  f32x4 acc[2][3];
  #pragma unroll
  for (int m = 0; m < 2; ++m)
    #pragma unroll
    for (int n = 0; n < 3; ++n)
      #pragma unroll
      for (int i = 0; i < 4; ++i) acc[m][n][i] = 0.f;

  float4 xv[2];
  bf16x8 wv[6];
  const int xrow = tid >> 3, xseg = tid & 7;   // 32 rows x 8 k-chunks

  auto load_tile = [&](int k0) {
    #pragma unroll
    for (int i = 0; i < 2; ++i)
      xv[i] = *(const float4*)&x[(r0 + xrow) * DIM + k0 + xseg * 8 + i * 4];
    #pragma unroll
    for (int i = 0; i < 6; ++i) {
      const int c = tid + i * 256, row = c >> 3, seg = c & 7;
      wv[i] = *(const bf16x8*)&Wt[row * DIM + k0 + seg * 8];
    }
  };
  auto write_tile = [&]() {
    bf16x8 t;
    #pragma unroll
    for (int i = 0; i < 2; ++i) {
      t[i * 4 + 0] = f2bf(xv[i].x); t[i * 4 + 1] = f2bf(xv[i].y);
      t[i * 4 + 2] = f2bf(xv[i].z); t[i * 4 + 3] = f2bf(xv[i].w);
    }
    *(bf16x8*)&xs[xrow * 72 + xseg * 8] = t;
    #pragma unroll
    for (int i = 0; i < 6; ++i) {
      const int c = tid + i * 256, row = c >> 3, seg = c & 7;
      *(bf16x8*)&ws[row * 72 + seg * 8] = wv[i];
    }
  };

  load_tile(0);
  write_tile();
  __syncthreads();

  for (int kt = 0; kt < 8; ++kt) {
    if (kt < 7) load_tile((kt + 1) * 64);

    #pragma unroll
    for (int kk = 0; kk < 2; ++kk) {
      bf16x8 a[2], b[3];
      #pragma unroll
      for (int m = 0; m < 2; ++m)
        a[m] = *(const bf16x8*)&xs[(m * 16 + lc) * 72 + kk * 32 + lg * 8];
      #pragma unroll
      for (int n = 0; n < 3; ++n)
        b[n] = *(const bf16x8*)&ws[(w * 48 + n * 16 + lc) * 72 + kk * 32 + lg * 8];
      __builtin_amdgcn_s_setprio(1);
      #pragma unroll
      for (int m = 0; m < 2; ++m)
        #pragma unroll
        for (int n = 0; n < 3; ++n)
          acc[m][n] = __builtin_amdgcn_mfma_f32_16x16x32_bf16(a[m], b[n], acc[m][n], 0, 0, 0);
      __builtin_amdgcn_s_setprio(0);
    }

    __syncthreads();
    if (kt < 7) {
      write_tile();
      __syncthreads();
    }
  }

  #pragma unroll
  for (int n = 0; n < 3; ++n) {
    const int col = w * 48 + n * 16 + lc;
    const int mat = col >> 6;
    const int h   = col & 63;
    const float bias = (mat == 0 ? bq : (mat == 1 ? bk : bv))[h];
    #pragma unroll
    for (int m = 0; m < 2; ++m)
      #pragma unroll
      for (int r = 0; r < 4; ++r) {
        const long row = r0 + m * 16 + lg * 4 + r;
        const short o = f2bf(acc[m][n][r] + bias);
        if (mat == 0)      Qb[row * HD + h] = o;
        else if (mat == 1) Kb[row * HD + h] = o;
        else {
          const int bb = (int)(row >> 11), t = (int)(row & 2047);
          Vt[((long)bb * HD + h) * SEQ + t] = o;
        }
      }
  }
}

// ---------------- Kernel 2: flash attention, split-8, single-buffer, 8 blk/CU
// R15 per-wave body. New (R18): single-buffered K/V LDS (16 KB) + split-8
// (grid 2048) -> 8 blocks x 4 waves = 32 waves/CU (hardware max TLP).
// Single-buffer exposes stage latency within a block, but 8 co-resident
// blocks cross-cover (m114 MFMA/VALU co-schedule). XCD pinning kept.
template<bool SPLIT>
__global__ __launch_bounds__(256) void attn_kernel(
    const short* __restrict__ Qb, const short* __restrict__ Kb,
    const short* __restrict__ Vt, const float* __restrict__ maskF,
    float* __restrict__ out, short* __restrict__ Opartb, float* __restrict__ ml)
{
  __shared__ short kt_lds[64 * 64];   // [key][h], swizzled columns
  __shared__ short vt_lds[64 * 64];   // [h][key], swizzled columns

  const int bid = blockIdx.x;
  int b, qt, eighth;
  if (SPLIT) {
    b = bid & 7;                       // XCD pinning: bid%8 -> XCD -> batch
    const int rest = bid >> 3;         // 0..255
    eighth = rest >> 5;                // 0..7
    const int v = rest & 31;
    qt = (eighth & 1) ? 31 - v : v;    // co-resident blocks: qt = v,31-v,...
  } else {
    b = bid >> 5; qt = bid & 31; eighth = 0;
  }

  const int nkt      = qt + 1;
  const int kt_begin = SPLIT ? (nkt * eighth) >> 3 : 0;
  const int kt_end   = SPLIT ? (nkt * (eighth + 1)) >> 3 : nkt;
  const int q0       = qt * 64;
  const int tid      = threadIdx.x;

  if (SPLIT && kt_begin >= kt_end) {
    // empty eighth: zero bf16 partials + sentinel stats
    bf16x8 z;
    #pragma unroll
    for (int j = 0; j < 8; ++j) z[j] = 0;
    #pragma unroll
    for (int i = 0; i < 2; ++i) {
      const int idx = tid + i * 256;
      const int rr = idx >> 3;
      const long row = (long)b * SEQ + q0 + rr;
      *(bf16x8*)&Opartb[((long)eighth * ROWS + row) * HD + (idx & 7) * 8] = z;
    }
    if (tid < 64) {
      const long row = (long)b * SEQ + q0 + tid;
      ml[((long)eighth * ROWS + row) * 2 + 0] = NEGV;
      ml[((long)eighth * ROWS + row) * 2 + 1] = 0.f;
    }
    return;
  }

  const int w    = tid >> 6;
  const int lane = tid & 63;
  const int lc   = lane & 15;
  const int lg   = lane >> 4;

  const short* Kbase = Kb + (long)b * SEQ * HD;
  const short* Vbase = Vt + (long)b * HD * SEQ;
  const float* mfbase = maskF + (long)b * SEQ;

  // Q fragments (B-operand): n = lc = query, k = lg*8+j (+32s)
  bf16x8 qf[2];
  #pragma unroll
  for (int s = 0; s < 2; ++s)
    qf[s] = *(const bf16x8*)&Qb[((long)b * SEQ + q0 + w * 16 + lc) * HD + s * 32 + lg * 8];

  const float SC = 0.125f * 1.44269504f;

  auto stage = [&](int kt) {
    #pragma unroll
    for (int i = 0; i < 2; ++i) {
      const int rr = (w * 2 + i) * 8 + (lane >> 3);
      const int sc = ((lane & 7) * 16) ^ ((rr & 7) << 4);
      gload16((const char*)Kbase + ((kt * 64 + rr) * 128 + sc),
              (char*)&kt_lds[0] + (w * 2 + i) * 1024);
      gload16((const char*)Vbase + (rr * 4096 + kt * 128 + sc),
              (char*)&vt_lds[0] + (w * 2 + i) * 1024);
    }
  };

  f32x4 o[4];
  #pragma unroll
  for (int n = 0; n < 4; ++n)
    #pragma unroll
    for (int i = 0; i < 4; ++i) o[n][i] = 0.f;
  float m = NEGV, l = 0.f;

  stage(kt_begin);
  __syncthreads();

  for (int kt = kt_begin; kt < kt_end; ++kt) {
    // additive mask (exp2 domain), broadcast across lc lanes; issued early
    f32x4 madd[4];
    #pragma unroll
    for (int n = 0; n < 4; ++n)
      madd[n] = *(const f32x4*)&mfbase[kt * 64 + n * 16 + lg * 4];

    // --- S^T = K Q^T from LDS ---
    f32x4 sf[4];
    #pragma unroll
    for (int n = 0; n < 4; ++n) {
      const int row = n * 16 + lc;                 // key
      const int swz = (row & 7) << 4;
      const bf16x8 k0 = *(const bf16x8*)((const char*)&kt_lds[0] + row * 128 + ((lg * 16) ^ swz));
      const bf16x8 k1 = *(const bf16x8*)((const char*)&kt_lds[0] + row * 128 + ((64 + lg * 16) ^ swz));
      f32x4 acc;
      #pragma unroll
      for (int i = 0; i < 4; ++i) acc[i] = 0.f;
      __builtin_amdgcn_s_setprio(1);
      acc = __builtin_amdgcn_mfma_f32_16x16x32_bf16(k0, qf[0], acc, 0, 0, 0);
      acc = __builtin_amdgcn_mfma_f32_16x16x32_bf16(k1, qf[1], acc, 0, 0, 0);
      __builtin_amdgcn_s_setprio(0);
      sf[n] = acc;
    }

    // --- scale + padding mask: one fma per element ---
    #pragma unroll
    for (int n = 0; n < 4; ++n)
      #pragma unroll
      for (int r = 0; r < 4; ++r)
        sf[n][r] = fmaf(sf[n][r], SC, madd[n][r]);

    // --- causal: diag tiles only (wave-uniform branch) ---
    if (kt == qt) {
      const int ql = w * 16 + lc;
      #pragma unroll
      for (int n = 0; n < 4; ++n)
        #pragma unroll
        for (int r = 0; r < 4; ++r)
          if (n * 16 + lg * 4 + r > ql) sf[n][r] = NEGV;
    }

    // --- lane-local softmax max ---
    float tm = fmaxf(fmaxf(fmaxf(sf[0][0], sf[0][1]), fmaxf(sf[0][2], sf[0][3])),
                     fmaxf(fmaxf(sf[1][0], sf[1][1]), fmaxf(sf[1][2], sf[1][3])));
    tm = fmaxf(tm, fmaxf(fmaxf(fmaxf(sf[2][0], sf[2][1]), fmaxf(sf[2][2], sf[2][3])),
                         fmaxf(fmaxf(sf[3][0], sf[3][1]), fmaxf(sf[3][2], sf[3][3]))));
    tm = fmaxf(tm, __shfl_xor(tm, 16));
    tm = fmaxf(tm, __shfl_xor(tm, 32));

    // --- defer-rescale: only pay corr when some lane's max grew (exact) ---
    if (__any(tm > m)) {
      const float mn = fmaxf(m, tm);
      const float corr = exp2f(m - mn);
      m = mn;
      #pragma unroll
      for (int n = 0; n < 4; ++n)
        #pragma unroll
        for (int r = 0; r < 4; ++r)
          o[n][r] *= corr;
      l *= corr;
    }

    float rs = 0.f;
    #pragma unroll
    for (int n = 0; n < 4; ++n)
      #pragma unroll
      for (int r = 0; r < 4; ++r) {
        const float pv = exp2f(sf[n][r] - m);
        sf[n][r] = pv;
        rs += pv;
      }
    rs += __shfl_xor(rs, 16);
    rs += __shfl_xor(rs, 32);
    l += rs;

    // --- pack P and repack to B-operand (verified mapping) ---
    int pk[4][2];
    #pragma unroll
    for (int n = 0; n < 4; ++n)
      #pragma unroll
      for (int h = 0; h < 2; ++h)
        asm("v_cvt_pk_bf16_f32 %0, %1, %2"
            : "=v"(pk[n][h]) : "v"(sf[n][2 * h]), "v"(sf[n][2 * h + 1]));

    i32x4 pw[2];
    #pragma unroll
    for (int s = 0; s < 2; ++s)
      #pragma unroll
      for (int mm = 0; mm < 4; ++mm) {
        const int src = ((lg & 1) * 2 + (mm >> 1)) * 16 + lc;
        const int a0 = __shfl(pk[2 * s][mm & 1], src);
        const int a1 = __shfl(pk[2 * s + 1][mm & 1], src);
        pw[s][mm] = (lg & 2) ? a1 : a0;
      }
    const bf16x8 pb0 = __builtin_bit_cast(bf16x8, pw[0]);
    const bf16x8 pb1 = __builtin_bit_cast(bf16x8, pw[1]);

    // --- O^T += V^T P^T from LDS ---
    #pragma unroll
    for (int n = 0; n < 4; ++n) {
      const int row = n * 16 + lc;                 // V column h
      const int swz = (row & 7) << 4;
      const bf16x8 v0 = *(const bf16x8*)((const char*)&vt_lds[0] + row * 128 + ((lg * 16) ^ swz));
      const bf16x8 v1 = *(const bf16x8*)((const char*)&vt_lds[0] + row * 128 + ((64 + lg * 16) ^ swz));
      __builtin_amdgcn_s_setprio(1);
      o[n] = __builtin_amdgcn_mfma_f32_16x16x32_bf16(v0, pb0, o[n], 0, 0, 0);
      o[n] = __builtin_amdgcn_mfma_f32_16x16x32_bf16(v1, pb1, o[n], 0, 0, 0);
      __builtin_amdgcn_s_setprio(0);
    }

    __syncthreads();            // all waves done reading this tile
    if (kt + 1 < kt_end) {
      stage(kt + 1);            // refill the single buffer
      __syncthreads();          // staged loads drained before use
    }
  }

  // ---- epilogue: O^T layout: query = lc, h = n*16 + lg*4 + r ----
  const long qrow = (long)b * SEQ + q0 + w * 16 + lc;
  if (SPLIT) {
    const long prow = (long)eighth * ROWS + qrow;
    #pragma unroll
    for (int n = 0; n < 4; ++n) {
      bf16x4 t;
      #pragma unroll
      for (int i = 0; i < 4; ++i) t[i] = f2bf(o[n][i]);
      *(bf16x4*)&Opartb[prow * HD + n * 16 + lg * 4] = t;
    }
    if (lg == 0) {
      ml[prow * 2 + 0] = m;
      ml[prow * 2 + 1] = l;
    }
  } else {
    const float inv = 1.f / l;
    #pragma unroll
    for (int n = 0; n < 4; ++n) {
      f32x4 t = o[n];
      #pragma unroll
      for (int i = 0; i < 4; ++i) t[i] *= inv;
      *(f32x4*)&out[qrow * HD + n * 16 + lg * 4] = t;
    }
  }
}

// ---------------- Kernel 3: merge the eight split-K bf16 partials -----------
__global__ __launch_bounds__(256) void combine_kernel(
    const short* __restrict__ Opartb, const float* __restrict__ ml,
    float* __restrict__ out)
{
  const int g = blockIdx.x * 256 + threadIdx.x;   // ROWS*16 total
  const int row = g >> 4;
  const int c4  = (g & 15) << 2;
  float mq[8], lq[8];
  #pragma unroll
  for (int q = 0; q < 8; ++q) {
    mq[q] = ml[((long)q * ROWS + row) * 2 + 0];
    lq[q] = ml[((long)q * ROWS + row) * 2 + 1];
  }
  float M = NEGV;
  #pragma unroll
  for (int q = 0; q < 8; ++q) M = fmaxf(M, mq[q]);
  float wq[8], L = 0.f;
  #pragma unroll
  for (int q = 0; q < 8; ++q) { wq[q] = exp2f(mq[q] - M); L += lq[q] * wq[q]; }
  const float inv = 1.f / L;
  f32x4 r;
  #pragma unroll
  for (int j = 0; j < 4; ++j) r[j] = 0.f;
  #pragma unroll
  for (int q = 0; q < 8; ++q) {
    const u16x4 ov = *(const u16x4*)&Opartb[((long)q * ROWS + row) * HD + c4];
    #pragma unroll
    for (int j = 0; j < 4; ++j) r[j] += bf2f(ov[j]) * wq[q];
  }
  #pragma unroll
  for (int j = 0; j < 4; ++j) r[j] *= inv;
  *(f32x4*)&out[(long)row * HD + c4] = r;
}

extern "C" void kernel_launch(void* const* d_in, const int* in_sizes, int n_in,
                              void* d_out, int out_size, void* d_ws, size_t ws_size,
                              hipStream_t stream) {
  const float* x  = (const float*)d_in[0];
  const unsigned char* pmask = (const unsigned char*)d_in[1];
  const float* Wq = (const float*)d_in[2];
  const float* bq = (const float*)d_in[3];
  const float* Wk = (const float*)d_in[4];
  const float* bk = (const float*)d_in[5];
  const float* Wv = (const float*)d_in[6];
  const float* bv = (const float*)d_in[7];
  float* out = (float*)d_out;

  short* Qb = (short*)d_ws;                         // [B*T*H] bf16
  short* Kb = Qb + (size_t)ROWS * HD;               // [B*T*H] bf16
  short* Vt = Kb + (size_t)ROWS * HD;               // [B*H*T] bf16
  short* Wt = Vt + (size_t)ROWS * HD;               // [192*512] bf16
  float* maskF  = (float*)(Wt + 192 * DIM);         // [ROWS] f32 additive mask
  short* Opartb = (short*)(maskF + ROWS);           // [8][ROWS][HD] bf16
  float* ml     = (float*)(Opartb + 8ull * ROWS * HD); // [8][ROWS][2] f32

  const size_t need = ((size_t)3 * ROWS * HD + 192 * DIM) * 2 + (size_t)ROWS * 4 +
                      8ull * ROWS * HD * 2 + 8ull * ROWS * 2 * 4;
  const bool split = ws_size >= need;

  prep_w<<<dim3(24), dim3(256), 0, stream>>>(Wq, Wk, Wv, pmask, Wt, maskF);
  qkv_gemm<<<dim3(ROWS / 32), dim3(256), 0, stream>>>(
      x, Wt, bq, bk, bv, Qb, Kb, Vt);
  if (split) {
    attn_kernel<true><<<dim3(2048), dim3(256), 0, stream>>>(
        Qb, Kb, Vt, maskF, out, Opartb, ml);
    combine_kernel<<<dim3(ROWS * 16 / 256), dim3(256), 0, stream>>>(Opartb, ml, out);
  } else {
    attn_kernel<false><<<dim3(256), dim3(256), 0, stream>>>(
        Qb, Kb, Vt, maskF, out, Opartb, ml);
  }
}

// Round 19
// 45.395 us; speedup vs baseline: 1.0404x; 1.0404x over previous
//
#include <hip/hip_runtime.h>
#include <hip/hip_bf16.h>

#define BATCH 8
#define SEQ   2048
#define DIM   512
#define HD    64
#define NEGV  (-1e30f)
#define ROWS  (BATCH * SEQ)   // 16384

typedef float f32x4  __attribute__((ext_vector_type(4)));
typedef int   i32x4  __attribute__((ext_vector_type(4)));
typedef short bf16x8 __attribute__((ext_vector_type(8)));
typedef short bf16x4 __attribute__((ext_vector_type(4)));
typedef unsigned short u16x4 __attribute__((ext_vector_type(4)));

__device__ __forceinline__ short f2bf(float f) {
  unsigned u = __builtin_bit_cast(unsigned, f);
  u += 0x7fffu + ((u >> 16) & 1u);
  return (short)(u >> 16);
}
__device__ __forceinline__ float bf2f(unsigned short s) {
  return __builtin_bit_cast(float, (unsigned)s << 16);
}

// async global->LDS, 16B per lane; dest = wave-uniform base + lane*16
__device__ __forceinline__ void gload16(const void* gsrc, void* ldst) {
  __builtin_amdgcn_global_load_lds(
      (const __attribute__((address_space(1))) unsigned int*)gsrc,
      (__attribute__((address_space(3))) unsigned int*)ldst,
      16, 0, 0);
}

// ---------------- Kernel 0: W transpose+convert + additive mask -------------
__global__ __launch_bounds__(256) void prep_w(
    const float* __restrict__ Wq, const float* __restrict__ Wk,
    const float* __restrict__ Wv, const unsigned char* __restrict__ pmask,
    short* __restrict__ Wt, float* __restrict__ maskF)
{
  __shared__ float lds[64][65];
  const int mat = blockIdx.x % 3;
  const int kb  = blockIdx.x / 3;
  const float* W = mat == 0 ? Wq : (mat == 1 ? Wk : Wv);
  const int tid = threadIdx.x;

  #pragma unroll
  for (int i = 0; i < 4; ++i) {
    const int kr = i * 16 + (tid >> 4);
    const int col = (tid & 15) * 4;
    *(float4*)&lds[kr][col] = *(const float4*)&W[(kb * 64 + kr) * HD + col];
  }
  __syncthreads();
  #pragma unroll
  for (int i = 0; i < 2; ++i) {
    const int c = tid + i * 256;
    const int n = c >> 3, seg = c & 7;
    bf16x8 o;
    #pragma unroll
    for (int j = 0; j < 8; ++j) o[j] = f2bf(lds[seg * 8 + j][n]);
    *(bf16x8*)&Wt[(mat * 64 + n) * DIM + kb * 64 + seg * 8] = o;
  }

  // additive mask in exp2 domain: pmask ? -1e30*log2(e) : 0
  for (int i = blockIdx.x * 256 + tid; i < ROWS; i += 24 * 256)
    maskF[i] = pmask[i] ? -1.442695041e30f : 0.f;
}

// ---------------- Kernel 1: QKV via MFMA, 256 thr, 32-row tile, BK=64 -------
// Grid 512 = 2 blocks/CU (R17). R19: s_setprio REMOVED (m190: setprio hurts
// lockstep barrier-synced MFMA kernels; never A/B'd here before).
__global__ __launch_bounds__(256) void qkv_gemm(
    const float* __restrict__ x, const short* __restrict__ Wt,
    const float* __restrict__ bq, const float* __restrict__ bk,
    const float* __restrict__ bv,
    short* __restrict__ Qb, short* __restrict__ Kb, short* __restrict__ Vt)
{
  __shared__ short xs[32 * 72];    // [row][k], padded stride 72
  __shared__ short ws[192 * 72];   // [col][k]

  const int tid  = threadIdx.x;
  const int lane = tid & 63;
  const int w    = tid >> 6;       // 0..3: cols w*48..+47
  const int lc   = lane & 15;
  const int lg   = lane >> 4;
  const long r0  = (long)blockIdx.x * 32;

  f32x4 acc[2][3];
  #pragma unroll
  for (int m = 0; m < 2; ++m)
    #pragma unroll
    for (int n = 0; n < 3; ++n)
      #pragma unroll
      for (int i = 0; i < 4; ++i) acc[m][n][i] = 0.f;

  float4 xv[2];
  bf16x8 wv[6];
  const int xrow = tid >> 3, xseg = tid & 7;   // 32 rows x 8 k-chunks

  auto load_tile = [&](int k0) {
    #pragma unroll
    for (int i = 0; i < 2; ++i)
      xv[i] = *(const float4*)&x[(r0 + xrow) * DIM + k0 + xseg * 8 + i * 4];
    #pragma unroll
    for (int i = 0; i < 6; ++i) {
      const int c = tid + i * 256, row = c >> 3, seg = c & 7;
      wv[i] = *(const bf16x8*)&Wt[row * DIM + k0 + seg * 8];
    }
  };
  auto write_tile = [&]() {
    bf16x8 t;
    #pragma unroll
    for (int i = 0; i < 2; ++i) {
      t[i * 4 + 0] = f2bf(xv[i].x); t[i * 4 + 1] = f2bf(xv[i].y);
      t[i * 4 + 2] = f2bf(xv[i].z); t[i * 4 + 3] = f2bf(xv[i].w);
    }
    *(bf16x8*)&xs[xrow * 72 + xseg * 8] = t;
    #pragma unroll
    for (int i = 0; i < 6; ++i) {
      const int c = tid + i * 256, row = c >> 3, seg = c & 7;
      *(bf16x8*)&ws[row * 72 + seg * 8] = wv[i];
    }
  };

  load_tile(0);
  write_tile();
  __syncthreads();

  for (int kt = 0; kt < 8; ++kt) {
    if (kt < 7) load_tile((kt + 1) * 64);

    #pragma unroll
    for (int kk = 0; kk < 2; ++kk) {
      bf16x8 a[2], b[3];
      #pragma unroll
      for (int m = 0; m < 2; ++m)
        a[m] = *(const bf16x8*)&xs[(m * 16 + lc) * 72 + kk * 32 + lg * 8];
      #pragma unroll
      for (int n = 0; n < 3; ++n)
        b[n] = *(const bf16x8*)&ws[(w * 48 + n * 16 + lc) * 72 + kk * 32 + lg * 8];
      #pragma unroll
      for (int m = 0; m < 2; ++m)
        #pragma unroll
        for (int n = 0; n < 3; ++n)
          acc[m][n] = __builtin_amdgcn_mfma_f32_16x16x32_bf16(a[m], b[n], acc[m][n], 0, 0, 0);
    }

    __syncthreads();
    if (kt < 7) {
      write_tile();
      __syncthreads();
    }
  }

  #pragma unroll
  for (int n = 0; n < 3; ++n) {
    const int col = w * 48 + n * 16 + lc;
    const int mat = col >> 6;
    const int h   = col & 63;
    const float bias = (mat == 0 ? bq : (mat == 1 ? bk : bv))[h];
    #pragma unroll
    for (int m = 0; m < 2; ++m)
      #pragma unroll
      for (int r = 0; r < 4; ++r) {
        const long row = r0 + m * 16 + lg * 4 + r;
        const short o = f2bf(acc[m][n][r] + bias);
        if (mat == 0)      Qb[row * HD + h] = o;
        else if (mat == 1) Kb[row * HD + h] = o;
        else {
          const int bb = (int)(row >> 11), t = (int)(row & 2047);
          Vt[((long)bb * HD + h) * SEQ + t] = o;
        }
      }
  }
}

// ---------------- Kernel 2: flash attention, split-4, XCD-pinned batch ------
// R15/R17 structure. R19 single change: all s_setprio removed (T5 is
// structure-conditional; hurts lockstep barrier kernels per m190).
template<bool SPLIT>
__global__ __launch_bounds__(256) void attn_kernel(
    const short* __restrict__ Qb, const short* __restrict__ Kb,
    const short* __restrict__ Vt, const float* __restrict__ maskF,
    float* __restrict__ out, short* __restrict__ Opartb, float* __restrict__ ml)
{
  __shared__ short kt_lds[2][64 * 64];   // [buf][key][h], swizzled columns
  __shared__ short vt_lds[2][64 * 64];   // [buf][h][key], swizzled columns

  const int bid = blockIdx.x;
  int b, qt, quarter;
  if (SPLIT) {
    b = bid & 7;                         // XCD pinning: bid%8 -> XCD -> batch
    const int rest = bid >> 3;           // 0..127
    quarter = rest >> 5;                 // 0..3
    const int v = rest & 31;
    qt = (quarter & 1) ? 31 - v : v;     // mirrored: co-resident blocks pair
  } else {
    b = bid >> 5; qt = bid & 31; quarter = 0;
  }

  const int nkt      = qt + 1;
  const int kt_begin = SPLIT ? (nkt * quarter) >> 2 : 0;
  const int kt_end   = SPLIT ? (nkt * (quarter + 1)) >> 2 : nkt;
  const int q0       = qt * 64;
  const int tid      = threadIdx.x;

  if (SPLIT && kt_begin >= kt_end) {
    bf16x8 z;
    #pragma unroll
    for (int j = 0; j < 8; ++j) z[j] = 0;
    #pragma unroll
    for (int i = 0; i < 2; ++i) {
      const int idx = tid + i * 256;
      const int rr = idx >> 3;
      const long row = (long)b * SEQ + q0 + rr;
      *(bf16x8*)&Opartb[((long)quarter * ROWS + row) * HD + (idx & 7) * 8] = z;
    }
    if (tid < 64) {
      const long row = (long)b * SEQ + q0 + tid;
      ml[((long)quarter * ROWS + row) * 2 + 0] = NEGV;
      ml[((long)quarter * ROWS + row) * 2 + 1] = 0.f;
    }
    return;
  }

  const int w    = tid >> 6;
  const int lane = tid & 63;
  const int lc   = lane & 15;
  const int lg   = lane >> 4;

  const short* Kbase = Kb + (long)b * SEQ * HD;
  const short* Vbase = Vt + (long)b * HD * SEQ;
  const float* mfbase = maskF + (long)b * SEQ;

  // Q fragments (B-operand): n = lc = query, k = lg*8+j (+32s)
  bf16x8 qf[2];
  #pragma unroll
  for (int s = 0; s < 2; ++s)
    qf[s] = *(const bf16x8*)&Qb[((long)b * SEQ + q0 + w * 16 + lc) * HD + s * 32 + lg * 8];

  const float SC = 0.125f * 1.44269504f;

  auto stage = [&](int buf, int kt) {
    #pragma unroll
    for (int i = 0; i < 2; ++i) {
      const int rr = (w * 2 + i) * 8 + (lane >> 3);
      const int sc = ((lane & 7) * 16) ^ ((rr & 7) << 4);
      gload16((const char*)Kbase + ((kt * 64 + rr) * 128 + sc),
              (char*)&kt_lds[buf][0] + (w * 2 + i) * 1024);
      gload16((const char*)Vbase + (rr * 4096 + kt * 128 + sc),
              (char*)&vt_lds[buf][0] + (w * 2 + i) * 1024);
    }
  };

  f32x4 o[4];
  #pragma unroll
  for (int n = 0; n < 4; ++n)
    #pragma unroll
    for (int i = 0; i < 4; ++i) o[n][i] = 0.f;
  float m = NEGV, l = 0.f;

  int buf = 0;
  stage(0, kt_begin);
  __syncthreads();

  for (int kt = kt_begin; kt < kt_end; ++kt) {
    if (kt + 1 < kt_end) stage(buf ^ 1, kt + 1);

    // additive mask (exp2 domain), broadcast across lc lanes; issued early
    f32x4 madd[4];
    #pragma unroll
    for (int n = 0; n < 4; ++n)
      madd[n] = *(const f32x4*)&mfbase[kt * 64 + n * 16 + lg * 4];

    // --- S^T = K Q^T from LDS ---
    f32x4 sf[4];
    #pragma unroll
    for (int n = 0; n < 4; ++n) {
      const int row = n * 16 + lc;                 // key
      const int swz = (row & 7) << 4;
      const bf16x8 k0 = *(const bf16x8*)((const char*)&kt_lds[buf][0] + row * 128 + ((lg * 16) ^ swz));
      const bf16x8 k1 = *(const bf16x8*)((const char*)&kt_lds[buf][0] + row * 128 + ((64 + lg * 16) ^ swz));
      f32x4 acc;
      #pragma unroll
      for (int i = 0; i < 4; ++i) acc[i] = 0.f;
      acc = __builtin_amdgcn_mfma_f32_16x16x32_bf16(k0, qf[0], acc, 0, 0, 0);
      acc = __builtin_amdgcn_mfma_f32_16x16x32_bf16(k1, qf[1], acc, 0, 0, 0);
      sf[n] = acc;
    }

    // --- scale + padding mask: one fma per element ---
    #pragma unroll
    for (int n = 0; n < 4; ++n)
      #pragma unroll
      for (int r = 0; r < 4; ++r)
        sf[n][r] = fmaf(sf[n][r], SC, madd[n][r]);

    // --- causal: diag tiles only (wave-uniform branch) ---
    if (kt == qt) {
      const int ql = w * 16 + lc;
      #pragma unroll
      for (int n = 0; n < 4; ++n)
        #pragma unroll
        for (int r = 0; r < 4; ++r)
          if (n * 16 + lg * 4 + r > ql) sf[n][r] = NEGV;
    }

    // --- lane-local softmax max ---
    float tm = fmaxf(fmaxf(fmaxf(sf[0][0], sf[0][1]), fmaxf(sf[0][2], sf[0][3])),
                     fmaxf(fmaxf(sf[1][0], sf[1][1]), fmaxf(sf[1][2], sf[1][3])));
    tm = fmaxf(tm, fmaxf(fmaxf(fmaxf(sf[2][0], sf[2][1]), fmaxf(sf[2][2], sf[2][3])),
                         fmaxf(fmaxf(sf[3][0], sf[3][1]), fmaxf(sf[3][2], sf[3][3]))));
    tm = fmaxf(tm, __shfl_xor(tm, 16));
    tm = fmaxf(tm, __shfl_xor(tm, 32));

    // --- defer-rescale: only pay corr when some lane's max grew (exact) ---
    if (__any(tm > m)) {
      const float mn = fmaxf(m, tm);
      const float corr = exp2f(m - mn);
      m = mn;
      #pragma unroll
      for (int n = 0; n < 4; ++n)
        #pragma unroll
        for (int r = 0; r < 4; ++r)
          o[n][r] *= corr;
      l *= corr;
    }

    float rs = 0.f;
    #pragma unroll
    for (int n = 0; n < 4; ++n)
      #pragma unroll
      for (int r = 0; r < 4; ++r) {
        const float pv = exp2f(sf[n][r] - m);
        sf[n][r] = pv;
        rs += pv;
      }
    rs += __shfl_xor(rs, 16);
    rs += __shfl_xor(rs, 32);
    l += rs;

    // --- pack P and repack to B-operand (verified mapping) ---
    int pk[4][2];
    #pragma unroll
    for (int n = 0; n < 4; ++n)
      #pragma unroll
      for (int h = 0; h < 2; ++h)
        asm("v_cvt_pk_bf16_f32 %0, %1, %2"
            : "=v"(pk[n][h]) : "v"(sf[n][2 * h]), "v"(sf[n][2 * h + 1]));

    i32x4 pw[2];
    #pragma unroll
    for (int s = 0; s < 2; ++s)
      #pragma unroll
      for (int mm = 0; mm < 4; ++mm) {
        const int src = ((lg & 1) * 2 + (mm >> 1)) * 16 + lc;
        const int a0 = __shfl(pk[2 * s][mm & 1], src);
        const int a1 = __shfl(pk[2 * s + 1][mm & 1], src);
        pw[s][mm] = (lg & 2) ? a1 : a0;
      }
    const bf16x8 pb0 = __builtin_bit_cast(bf16x8, pw[0]);
    const bf16x8 pb1 = __builtin_bit_cast(bf16x8, pw[1]);

    // --- O^T += V^T P^T from LDS ---
    #pragma unroll
    for (int n = 0; n < 4; ++n) {
      const int row = n * 16 + lc;                 // V column h
      const int swz = (row & 7) << 4;
      const bf16x8 v0 = *(const bf16x8*)((const char*)&vt_lds[buf][0] + row * 128 + ((lg * 16) ^ swz));
      const bf16x8 v1 = *(const bf16x8*)((const char*)&vt_lds[buf][0] + row * 128 + ((64 + lg * 16) ^ swz));
      o[n] = __builtin_amdgcn_mfma_f32_16x16x32_bf16(v0, pb0, o[n], 0, 0, 0);
      o[n] = __builtin_amdgcn_mfma_f32_16x16x32_bf16(v1, pb1, o[n], 0, 0, 0);
    }

    __syncthreads();     // drains staged loads + all waves done with buf
    buf ^= 1;
  }

  // ---- epilogue: O^T layout: query = lc, h = n*16 + lg*4 + r ----
  const long qrow = (long)b * SEQ + q0 + w * 16 + lc;
  if (SPLIT) {
    const long prow = (long)quarter * ROWS + qrow;
    #pragma unroll
    for (int n = 0; n < 4; ++n) {
      bf16x4 t;
      #pragma unroll
      for (int i = 0; i < 4; ++i) t[i] = f2bf(o[n][i]);
      *(bf16x4*)&Opartb[prow * HD + n * 16 + lg * 4] = t;
    }
    if (lg == 0) {
      ml[prow * 2 + 0] = m;
      ml[prow * 2 + 1] = l;
    }
  } else {
    const float inv = 1.f / l;
    #pragma unroll
    for (int n = 0; n < 4; ++n) {
      f32x4 t = o[n];
      #pragma unroll
      for (int i = 0; i < 4; ++i) t[i] *= inv;
      *(f32x4*)&out[qrow * HD + n * 16 + lg * 4] = t;
    }
  }
}

// ---------------- Kernel 3: merge the four split-K bf16 partials ------------
__global__ __launch_bounds__(256) void combine_kernel(
    const short* __restrict__ Opartb, const float* __restrict__ ml,
    float* __restrict__ out)
{
  const int g = blockIdx.x * 256 + threadIdx.x;   // ROWS*16 total
  const int row = g >> 4;
  const int c4  = (g & 15) << 2;
  float mq[4], lq[4];
  #pragma unroll
  for (int q = 0; q < 4; ++q) {
    mq[q] = ml[((long)q * ROWS + row) * 2 + 0];
    lq[q] = ml[((long)q * ROWS + row) * 2 + 1];
  }
  const float M = fmaxf(fmaxf(mq[0], mq[1]), fmaxf(mq[2], mq[3]));
  float wq[4], L = 0.f;
  #pragma unroll
  for (int q = 0; q < 4; ++q) { wq[q] = exp2f(mq[q] - M); L += lq[q] * wq[q]; }
  const float inv = 1.f / L;
  f32x4 r;
  #pragma unroll
  for (int j = 0; j < 4; ++j) r[j] = 0.f;
  #pragma unroll
  for (int q = 0; q < 4; ++q) {
    const u16x4 ov = *(const u16x4*)&Opartb[((long)q * ROWS + row) * HD + c4];
    #pragma unroll
    for (int j = 0; j < 4; ++j) r[j] += bf2f(ov[j]) * wq[q];
  }
  #pragma unroll
  for (int j = 0; j < 4; ++j) r[j] *= inv;
  *(f32x4*)&out[(long)row * HD + c4] = r;
}

extern "C" void kernel_launch(void* const* d_in, const int* in_sizes, int n_in,
                              void* d_out, int out_size, void* d_ws, size_t ws_size,
                              hipStream_t stream) {
  const float* x  = (const float*)d_in[0];
  const unsigned char* pmask = (const unsigned char*)d_in[1];
  const float* Wq = (const float*)d_in[2];
  const float* bq = (const float*)d_in[3];
  const float* Wk = (const float*)d_in[4];
  const float* bk = (const float*)d_in[5];
  const float* Wv = (const float*)d_in[6];
  const float* bv = (const float*)d_in[7];
  float* out = (float*)d_out;

  short* Qb = (short*)d_ws;                         // [B*T*H] bf16
  short* Kb = Qb + (size_t)ROWS * HD;               // [B*T*H] bf16
  short* Vt = Kb + (size_t)ROWS * HD;               // [B*H*T] bf16
  short* Wt = Vt + (size_t)ROWS * HD;               // [192*512] bf16
  float* maskF  = (float*)(Wt + 192 * DIM);         // [ROWS] f32 additive mask
  short* Opartb = (short*)(maskF + ROWS);           // [4][ROWS][HD] bf16
  float* ml     = (float*)(Opartb + 4ull * ROWS * HD); // [4][ROWS][2] f32

  const size_t need = ((size_t)3 * ROWS * HD + 192 * DIM) * 2 + (size_t)ROWS * 4 +
                      4ull * ROWS * HD * 2 + 4ull * ROWS * 2 * 4;
  const bool split = ws_size >= need;

  prep_w<<<dim3(24), dim3(256), 0, stream>>>(Wq, Wk, Wv, pmask, Wt, maskF);
  qkv_gemm<<<dim3(ROWS / 32), dim3(256), 0, stream>>>(
      x, Wt, bq, bk, bv, Qb, Kb, Vt);
  if (split) {
    attn_kernel<true><<<dim3(1024), dim3(256), 0, stream>>>(
        Qb, Kb, Vt, maskF, out, Opartb, ml);
    combine_kernel<<<dim3(ROWS * 16 / 256), dim3(256), 0, stream>>>(Opartb, ml, out);
  } else {
    attn_kernel<false><<<dim3(256), dim3(256), 0, stream>>>(
        Qb, Kb, Vt, maskF, out, Opartb, ml);
  }
}

// Round 20
// 44.331 us; speedup vs baseline: 1.0654x; 1.0240x over previous
//
#include <hip/hip_runtime.h>
#include <hip/hip_bf16.h>

#define BATCH 8
#define SEQ   2048
#define DIM   512
#define HD    64
#define NEGV  (-1e30f)
#define ROWS  (BATCH * SEQ)   // 16384

typedef float f32x4  __attribute__((ext_vector_type(4)));
typedef int   i32x4  __attribute__((ext_vector_type(4)));
typedef short bf16x8 __attribute__((ext_vector_type(8)));
typedef short bf16x4 __attribute__((ext_vector_type(4)));
typedef unsigned short u16x4 __attribute__((ext_vector_type(4)));

__device__ __forceinline__ short f2bf(float f) {
  unsigned u = __builtin_bit_cast(unsigned, f);
  u += 0x7fffu + ((u >> 16) & 1u);
  return (short)(u >> 16);
}
__device__ __forceinline__ float bf2f(unsigned short s) {
  return __builtin_bit_cast(float, (unsigned)s << 16);
}

// async global->LDS, 16B per lane; dest = wave-uniform base + lane*16
__device__ __forceinline__ void gload16(const void* gsrc, void* ldst) {
  __builtin_amdgcn_global_load_lds(
      (const __attribute__((address_space(1))) unsigned int*)gsrc,
      (__attribute__((address_space(3))) unsigned int*)ldst,
      16, 0, 0);
}

// ---------------- Kernel 0: W transpose+convert + additive mask -------------
__global__ __launch_bounds__(256) void prep_w(
    const float* __restrict__ Wq, const float* __restrict__ Wk,
    const float* __restrict__ Wv, const unsigned char* __restrict__ pmask,
    short* __restrict__ Wt, float* __restrict__ maskF)
{
  __shared__ float lds[64][65];
  const int mat = blockIdx.x % 3;
  const int kb  = blockIdx.x / 3;
  const float* W = mat == 0 ? Wq : (mat == 1 ? Wk : Wv);
  const int tid = threadIdx.x;

  #pragma unroll
  for (int i = 0; i < 4; ++i) {
    const int kr = i * 16 + (tid >> 4);
    const int col = (tid & 15) * 4;
    *(float4*)&lds[kr][col] = *(const float4*)&W[(kb * 64 + kr) * HD + col];
  }
  __syncthreads();
  #pragma unroll
  for (int i = 0; i < 2; ++i) {
    const int c = tid + i * 256;
    const int n = c >> 3, seg = c & 7;
    bf16x8 o;
    #pragma unroll
    for (int j = 0; j < 8; ++j) o[j] = f2bf(lds[seg * 8 + j][n]);
    *(bf16x8*)&Wt[(mat * 64 + n) * DIM + kb * 64 + seg * 8] = o;
  }

  // additive mask in exp2 domain: pmask ? -1e30*log2(e) : 0
  for (int i = blockIdx.x * 256 + tid; i < ROWS; i += 24 * 256)
    maskF[i] = pmask[i] ? -1.442695041e30f : 0.f;
}

// ---------------- Kernel 1: QKV via MFMA, 256 thr, 32-row tile, BK=64 -------
__global__ __launch_bounds__(256) void qkv_gemm(
    const float* __restrict__ x, const short* __restrict__ Wt,
    const float* __restrict__ bq, const float* __restrict__ bk,
    const float* __restrict__ bv,
    short* __restrict__ Qb, short* __restrict__ Kb, short* __restrict__ Vt)
{
  __shared__ short xs[32 * 72];    // [row][k], padded stride 72
  __shared__ short ws[192 * 72];   // [col][k]

  const int tid  = threadIdx.x;
  const int lane = tid & 63;
  const int w    = tid >> 6;       // 0..3: cols w*48..+47
  const int lc   = lane & 15;
  const int lg   = lane >> 4;
  const long r0  = (long)blockIdx.x * 32;

  f32x4 acc[2][3];
  #pragma unroll
  for (int m = 0; m < 2; ++m)
    #pragma unroll
    for (int n = 0; n < 3; ++n)
      #pragma unroll
      for (int i = 0; i < 4; ++i) acc[m][n][i] = 0.f;

  float4 xv[2];
  bf16x8 wv[6];
  const int xrow = tid >> 3, xseg = tid & 7;   // 32 rows x 8 k-chunks

  auto load_tile = [&](int k0) {
    #pragma unroll
    for (int i = 0; i < 2; ++i)
      xv[i] = *(const float4*)&x[(r0 + xrow) * DIM + k0 + xseg * 8 + i * 4];
    #pragma unroll
    for (int i = 0; i < 6; ++i) {
      const int c = tid + i * 256, row = c >> 3, seg = c & 7;
      wv[i] = *(const bf16x8*)&Wt[row * DIM + k0 + seg * 8];
    }
  };
  auto write_tile = [&]() {
    bf16x8 t;
    #pragma unroll
    for (int i = 0; i < 2; ++i) {
      t[i * 4 + 0] = f2bf(xv[i].x); t[i * 4 + 1] = f2bf(xv[i].y);
      t[i * 4 + 2] = f2bf(xv[i].z); t[i * 4 + 3] = f2bf(xv[i].w);
    }
    *(bf16x8*)&xs[xrow * 72 + xseg * 8] = t;
    #pragma unroll
    for (int i = 0; i < 6; ++i) {
      const int c = tid + i * 256, row = c >> 3, seg = c & 7;
      *(bf16x8*)&ws[row * 72 + seg * 8] = wv[i];
    }
  };

  load_tile(0);
  write_tile();
  __syncthreads();

  for (int kt = 0; kt < 8; ++kt) {
    if (kt < 7) load_tile((kt + 1) * 64);

    #pragma unroll
    for (int kk = 0; kk < 2; ++kk) {
      bf16x8 a[2], b[3];
      #pragma unroll
      for (int m = 0; m < 2; ++m)
        a[m] = *(const bf16x8*)&xs[(m * 16 + lc) * 72 + kk * 32 + lg * 8];
      #pragma unroll
      for (int n = 0; n < 3; ++n)
        b[n] = *(const bf16x8*)&ws[(w * 48 + n * 16 + lc) * 72 + kk * 32 + lg * 8];
      #pragma unroll
      for (int m = 0; m < 2; ++m)
        #pragma unroll
        for (int n = 0; n < 3; ++n)
          acc[m][n] = __builtin_amdgcn_mfma_f32_16x16x32_bf16(a[m], b[n], acc[m][n], 0, 0, 0);
    }

    __syncthreads();
    if (kt < 7) {
      write_tile();
      __syncthreads();
    }
  }

  #pragma unroll
  for (int n = 0; n < 3; ++n) {
    const int col = w * 48 + n * 16 + lc;
    const int mat = col >> 6;
    const int h   = col & 63;
    const float bias = (mat == 0 ? bq : (mat == 1 ? bk : bv))[h];
    #pragma unroll
    for (int m = 0; m < 2; ++m)
      #pragma unroll
      for (int r = 0; r < 4; ++r) {
        const long row = r0 + m * 16 + lg * 4 + r;
        const short o = f2bf(acc[m][n][r] + bias);
        if (mat == 0)      Qb[row * HD + h] = o;
        else if (mat == 1) Kb[row * HD + h] = o;
        else {
          const int bb = (int)(row >> 11), t = (int)(row & 2047);
          Vt[((long)bb * HD + h) * SEQ + t] = o;
        }
      }
  }
}

// ---------------- Kernel 2: flash attention, split-4, XCD-pinned batch ------
// R19 structure. R20: (1) l kept as per-lane partial (sum-reduce shuffles
// moved out of the loop to the epilogue); (2) V LDS reads hoisted before
// softmax so they complete under the max-reduce/exp2 chain.
template<bool SPLIT>
__global__ __launch_bounds__(256) void attn_kernel(
    const short* __restrict__ Qb, const short* __restrict__ Kb,
    const short* __restrict__ Vt, const float* __restrict__ maskF,
    float* __restrict__ out, short* __restrict__ Opartb, float* __restrict__ ml)
{
  __shared__ short kt_lds[2][64 * 64];   // [buf][key][h], swizzled columns
  __shared__ short vt_lds[2][64 * 64];   // [buf][h][key], swizzled columns

  const int bid = blockIdx.x;
  int b, qt, quarter;
  if (SPLIT) {
    b = bid & 7;                         // XCD pinning: bid%8 -> XCD -> batch
    const int rest = bid >> 3;           // 0..127
    quarter = rest >> 5;                 // 0..3
    const int v = rest & 31;
    qt = (quarter & 1) ? 31 - v : v;     // mirrored: co-resident blocks pair
  } else {
    b = bid >> 5; qt = bid & 31; quarter = 0;
  }

  const int nkt      = qt + 1;
  const int kt_begin = SPLIT ? (nkt * quarter) >> 2 : 0;
  const int kt_end   = SPLIT ? (nkt * (quarter + 1)) >> 2 : nkt;
  const int q0       = qt * 64;
  const int tid      = threadIdx.x;

  if (SPLIT && kt_begin >= kt_end) {
    bf16x8 z;
    #pragma unroll
    for (int j = 0; j < 8; ++j) z[j] = 0;
    #pragma unroll
    for (int i = 0; i < 2; ++i) {
      const int idx = tid + i * 256;
      const int rr = idx >> 3;
      const long row = (long)b * SEQ + q0 + rr;
      *(bf16x8*)&Opartb[((long)quarter * ROWS + row) * HD + (idx & 7) * 8] = z;
    }
    if (tid < 64) {
      const long row = (long)b * SEQ + q0 + tid;
      ml[((long)quarter * ROWS + row) * 2 + 0] = NEGV;
      ml[((long)quarter * ROWS + row) * 2 + 1] = 0.f;
    }
    return;
  }

  const int w    = tid >> 6;
  const int lane = tid & 63;
  const int lc   = lane & 15;
  const int lg   = lane >> 4;

  const short* Kbase = Kb + (long)b * SEQ * HD;
  const short* Vbase = Vt + (long)b * HD * SEQ;
  const float* mfbase = maskF + (long)b * SEQ;

  // Q fragments (B-operand): n = lc = query, k = lg*8+j (+32s)
  bf16x8 qf[2];
  #pragma unroll
  for (int s = 0; s < 2; ++s)
    qf[s] = *(const bf16x8*)&Qb[((long)b * SEQ + q0 + w * 16 + lc) * HD + s * 32 + lg * 8];

  const float SC = 0.125f * 1.44269504f;

  auto stage = [&](int buf, int kt) {
    #pragma unroll
    for (int i = 0; i < 2; ++i) {
      const int rr = (w * 2 + i) * 8 + (lane >> 3);
      const int sc = ((lane & 7) * 16) ^ ((rr & 7) << 4);
      gload16((const char*)Kbase + ((kt * 64 + rr) * 128 + sc),
              (char*)&kt_lds[buf][0] + (w * 2 + i) * 1024);
      gload16((const char*)Vbase + (rr * 4096 + kt * 128 + sc),
              (char*)&vt_lds[buf][0] + (w * 2 + i) * 1024);
    }
  };

  f32x4 o[4];
  #pragma unroll
  for (int n = 0; n < 4; ++n)
    #pragma unroll
    for (int i = 0; i < 4; ++i) o[n][i] = 0.f;
  float m = NEGV, l = 0.f;   // l is a PER-LANE PARTIAL (this lane's 16 keys)

  int buf = 0;
  stage(0, kt_begin);
  __syncthreads();

  for (int kt = kt_begin; kt < kt_end; ++kt) {
    if (kt + 1 < kt_end) stage(buf ^ 1, kt + 1);

    // additive mask (exp2 domain), broadcast across lc lanes; issued early
    f32x4 madd[4];
    #pragma unroll
    for (int n = 0; n < 4; ++n)
      madd[n] = *(const f32x4*)&mfbase[kt * 64 + n * 16 + lg * 4];

    // --- S^T = K Q^T from LDS ---
    f32x4 sf[4];
    #pragma unroll
    for (int n = 0; n < 4; ++n) {
      const int row = n * 16 + lc;                 // key
      const int swz = (row & 7) << 4;
      const bf16x8 k0 = *(const bf16x8*)((const char*)&kt_lds[buf][0] + row * 128 + ((lg * 16) ^ swz));
      const bf16x8 k1 = *(const bf16x8*)((const char*)&kt_lds[buf][0] + row * 128 + ((64 + lg * 16) ^ swz));
      f32x4 acc;
      #pragma unroll
      for (int i = 0; i < 4; ++i) acc[i] = 0.f;
      acc = __builtin_amdgcn_mfma_f32_16x16x32_bf16(k0, qf[0], acc, 0, 0, 0);
      acc = __builtin_amdgcn_mfma_f32_16x16x32_bf16(k1, qf[1], acc, 0, 0, 0);
      sf[n] = acc;
    }

    // --- V fragments: issue NOW so the reads complete under the softmax ---
    bf16x8 vf[4][2];
    #pragma unroll
    for (int n = 0; n < 4; ++n) {
      const int row = n * 16 + lc;                 // V column h
      const int swz = (row & 7) << 4;
      vf[n][0] = *(const bf16x8*)((const char*)&vt_lds[buf][0] + row * 128 + ((lg * 16) ^ swz));
      vf[n][1] = *(const bf16x8*)((const char*)&vt_lds[buf][0] + row * 128 + ((64 + lg * 16) ^ swz));
    }

    // --- scale + padding mask: one fma per element ---
    #pragma unroll
    for (int n = 0; n < 4; ++n)
      #pragma unroll
      for (int r = 0; r < 4; ++r)
        sf[n][r] = fmaf(sf[n][r], SC, madd[n][r]);

    // --- causal: diag tiles only (wave-uniform branch) ---
    if (kt == qt) {
      const int ql = w * 16 + lc;
      #pragma unroll
      for (int n = 0; n < 4; ++n)
        #pragma unroll
        for (int r = 0; r < 4; ++r)
          if (n * 16 + lg * 4 + r > ql) sf[n][r] = NEGV;
    }

    // --- lane-local softmax max (cross-lane: 2 shfl, unavoidable) ---
    float tm = fmaxf(fmaxf(fmaxf(sf[0][0], sf[0][1]), fmaxf(sf[0][2], sf[0][3])),
                     fmaxf(fmaxf(sf[1][0], sf[1][1]), fmaxf(sf[1][2], sf[1][3])));
    tm = fmaxf(tm, fmaxf(fmaxf(fmaxf(sf[2][0], sf[2][1]), fmaxf(sf[2][2], sf[2][3])),
                         fmaxf(fmaxf(sf[3][0], sf[3][1]), fmaxf(sf[3][2], sf[3][3]))));
    tm = fmaxf(tm, __shfl_xor(tm, 16));
    tm = fmaxf(tm, __shfl_xor(tm, 32));

    // --- defer-rescale: only pay corr when some lane's max grew (exact) ---
    if (__any(tm > m)) {
      const float mn = fmaxf(m, tm);
      const float corr = exp2f(m - mn);
      m = mn;
      #pragma unroll
      for (int n = 0; n < 4; ++n)
        #pragma unroll
        for (int r = 0; r < 4; ++r)
          o[n][r] *= corr;
      l *= corr;               // partial scales correctly (shared m)
    }

    // --- exp2 + per-lane partial sum (NO cross-lane reduce in the loop) ---
    float rs = 0.f;
    #pragma unroll
    for (int n = 0; n < 4; ++n)
      #pragma unroll
      for (int r = 0; r < 4; ++r) {
        const float pv = exp2f(sf[n][r] - m);
        sf[n][r] = pv;
        rs += pv;
      }
    l += rs;

    // --- pack P and repack to B-operand (verified mapping) ---
    int pk[4][2];
    #pragma unroll
    for (int n = 0; n < 4; ++n)
      #pragma unroll
      for (int h = 0; h < 2; ++h)
        asm("v_cvt_pk_bf16_f32 %0, %1, %2"
            : "=v"(pk[n][h]) : "v"(sf[n][2 * h]), "v"(sf[n][2 * h + 1]));

    i32x4 pw[2];
    #pragma unroll
    for (int s = 0; s < 2; ++s)
      #pragma unroll
      for (int mm = 0; mm < 4; ++mm) {
        const int src = ((lg & 1) * 2 + (mm >> 1)) * 16 + lc;
        const int a0 = __shfl(pk[2 * s][mm & 1], src);
        const int a1 = __shfl(pk[2 * s + 1][mm & 1], src);
        pw[s][mm] = (lg & 2) ? a1 : a0;
      }
    const bf16x8 pb0 = __builtin_bit_cast(bf16x8, pw[0]);
    const bf16x8 pb1 = __builtin_bit_cast(bf16x8, pw[1]);

    // --- O^T += V^T P^T (vf already in registers) ---
    #pragma unroll
    for (int n = 0; n < 4; ++n) {
      o[n] = __builtin_amdgcn_mfma_f32_16x16x32_bf16(vf[n][0], pb0, o[n], 0, 0, 0);
      o[n] = __builtin_amdgcn_mfma_f32_16x16x32_bf16(vf[n][1], pb1, o[n], 0, 0, 0);
    }

    __syncthreads();     // drains staged loads + all waves done with buf
    buf ^= 1;
  }

  // ---- one-time l merge across the 4 lg-groups (was per-iteration) ----
  l += __shfl_xor(l, 16);
  l += __shfl_xor(l, 32);

  // ---- epilogue: O^T layout: query = lc, h = n*16 + lg*4 + r ----
  const long qrow = (long)b * SEQ + q0 + w * 16 + lc;
  if (SPLIT) {
    const long prow = (long)quarter * ROWS + qrow;
    #pragma unroll
    for (int n = 0; n < 4; ++n) {
      bf16x4 t;
      #pragma unroll
      for (int i = 0; i < 4; ++i) t[i] = f2bf(o[n][i]);
      *(bf16x4*)&Opartb[prow * HD + n * 16 + lg * 4] = t;
    }
    if (lg == 0) {
      ml[prow * 2 + 0] = m;
      ml[prow * 2 + 1] = l;
    }
  } else {
    const float inv = 1.f / l;
    #pragma unroll
    for (int n = 0; n < 4; ++n) {
      f32x4 t = o[n];
      #pragma unroll
      for (int i = 0; i < 4; ++i) t[i] *= inv;
      *(f32x4*)&out[qrow * HD + n * 16 + lg * 4] = t;
    }
  }
}

// ---------------- Kernel 3: merge the four split-K bf16 partials ------------
__global__ __launch_bounds__(256) void combine_kernel(
    const short* __restrict__ Opartb, const float* __restrict__ ml,
    float* __restrict__ out)
{
  const int g = blockIdx.x * 256 + threadIdx.x;   // ROWS*16 total
  const int row = g >> 4;
  const int c4  = (g & 15) << 2;
  float mq[4], lq[4];
  #pragma unroll
  for (int q = 0; q < 4; ++q) {
    mq[q] = ml[((long)q * ROWS + row) * 2 + 0];
    lq[q] = ml[((long)q * ROWS + row) * 2 + 1];
  }
  const float M = fmaxf(fmaxf(mq[0], mq[1]), fmaxf(mq[2], mq[3]));
  float wq[4], L = 0.f;
  #pragma unroll
  for (int q = 0; q < 4; ++q) { wq[q] = exp2f(mq[q] - M); L += lq[q] * wq[q]; }
  const float inv = 1.f / L;
  f32x4 r;
  #pragma unroll
  for (int j = 0; j < 4; ++j) r[j] = 0.f;
  #pragma unroll
  for (int q = 0; q < 4; ++q) {
    const u16x4 ov = *(const u16x4*)&Opartb[((long)q * ROWS + row) * HD + c4];
    #pragma unroll
    for (int j = 0; j < 4; ++j) r[j] += bf2f(ov[j]) * wq[q];
  }
  #pragma unroll
  for (int j = 0; j < 4; ++j) r[j] *= inv;
  *(f32x4*)&out[(long)row * HD + c4] = r;
}

extern "C" void kernel_launch(void* const* d_in, const int* in_sizes, int n_in,
                              void* d_out, int out_size, void* d_ws, size_t ws_size,
                              hipStream_t stream) {
  const float* x  = (const float*)d_in[0];
  const unsigned char* pmask = (const unsigned char*)d_in[1];
  const float* Wq = (const float*)d_in[2];
  const float* bq = (const float*)d_in[3];
  const float* Wk = (const float*)d_in[4];
  const float* bk = (const float*)d_in[5];
  const float* Wv = (const float*)d_in[6];
  const float* bv = (const float*)d_in[7];
  float* out = (float*)d_out;

  short* Qb = (short*)d_ws;                         // [B*T*H] bf16
  short* Kb = Qb + (size_t)ROWS * HD;               // [B*T*H] bf16
  short* Vt = Kb + (size_t)ROWS * HD;               // [B*H*T] bf16
  short* Wt = Vt + (size_t)ROWS * HD;               // [192*512] bf16
  float* maskF  = (float*)(Wt + 192 * DIM);         // [ROWS] f32 additive mask
  short* Opartb = (short*)(maskF + ROWS);           // [4][ROWS][HD] bf16
  float* ml     = (float*)(Opartb + 4ull * ROWS * HD); // [4][ROWS][2] f32

  const size_t need = ((size_t)3 * ROWS * HD + 192 * DIM) * 2 + (size_t)ROWS * 4 +
                      4ull * ROWS * HD * 2 + 4ull * ROWS * 2 * 4;
  const bool split = ws_size >= need;

  prep_w<<<dim3(24), dim3(256), 0, stream>>>(Wq, Wk, Wv, pmask, Wt, maskF);
  qkv_gemm<<<dim3(ROWS / 32), dim3(256), 0, stream>>>(
      x, Wt, bq, bk, bv, Qb, Kb, Vt);
  if (split) {
    attn_kernel<true><<<dim3(1024), dim3(256), 0, stream>>>(
        Qb, Kb, Vt, maskF, out, Opartb, ml);
    combine_kernel<<<dim3(ROWS * 16 / 256), dim3(256), 0, stream>>>(Opartb, ml, out);
  } else {
    attn_kernel<false><<<dim3(256), dim3(256), 0, stream>>>(
        Qb, Kb, Vt, maskF, out, Opartb, ml);
  }
}